// Round 8
// baseline (56.205 us; speedup 1.0000x reference)
//
#include <hip/hip_runtime.h>
#include <stdint.h>

// Reference: pos += fl32(vel*dt); vel += fl32(fl32(-9.81)*fl32(0.01)); record pos.
// Exact emulation of the f32 scan via piecewise-constant-increment runs.
// r8 = r6 numerics (single anchor at NS=4e6, proven absmax 2^28) with the vel
// staircase built ANALYTICALLY (per-binade closed form, ~35 serial links, no
// ballot) + wave-parallel verification + r6 serial-ballot fallback on any
// verification failure. Phase 2 (pos run-events from NS) is r6 verbatim.
// r7 lesson: model-pos anchoring is only sound where the pos-quantization
// sawtooth (ulp^2/(8|cv*dt|)) is small — at 4e6 it is ~2.6e7; at 9e6 it is
// ~1.7e9 (the r7 failure). So: one anchor, at 4e6.

static constexpr long long NSTEPS = 10000000LL;  // output rows
static constexpr long long NS     = 4000000LL;   // model/event cutover (even)
static constexpr int SEGCAP  = 384;              // vel segments (~70 real)
static constexpr int RUNCAP  = 1024;             // pos runs (~15 real)
static constexpr int RUN_LDS = 512;

__device__ __forceinline__ bool same_binade_f32(float a, float b) {
    return (((__float_as_uint(a) ^ __float_as_uint(b)) & 0xFF800000u) == 0u);
}

__global__ __launch_bounds__(64) void prepass(
        const float* __restrict__ pos0, const float* __restrict__ vel0,
        int* __restrict__ counts,
        int* __restrict__ g_segm, double* __restrict__ g_segV,
        double* __restrict__ g_segc, double* __restrict__ g_segP,
        int* __restrict__ g_rn0, double* __restrict__ g_rpos,
        double* __restrict__ g_rinc, int runcap)
{
    __shared__ int    s_m[SEGCAP + 1];
    __shared__ double s_c[SEGCAP], s_V[SEGCAP], s_P[SEGCAP];
    __shared__ int    s_nseg, s_bad;

    const int lane = threadIdx.x;
    const float dtf  = 0.01f;
    const float gdtf = __fmul_rn(-9.81f, dtf);
    const double dtd = (double)dtf, gcd = (double)gdtf;

    // ===== Phase 1a (lane 0): ANALYTIC vel staircase ========================
    // Within a binade, fl(v+gc)-v = quantize(gc, ulp) is the same for every
    // grid point v (non-tie) -> one main segment per binade (length from one
    // exact f64 divide) + a 1-step boundary segment computed with direct f32.
    if (lane == 0) {
        s_bad = 0;
        double V = (double)vel0[1];
        double P = (double)pos0[1];   // model pos prefix: p0 + dt*sum(vel_k)
        long long m = 0;
        int nseg = 0, guard = 0;
        while (m < NSTEPS) {
            if (++guard > 300 || nseg >= SEGCAP - 2) { s_bad = 1; break; }
            const float vf = (float)V;
            if ((double)vf != V) { s_bad = 1; break; }      // must be on f32 grid
            const float vn1 = __fadd_rn(vf, gdtf);
            const double c = (double)vn1 - V;
            if (!(c < 0.0)) { s_bad = 1; break; }           // gravity: strictly down
            const long long rem = NSTEPS - m;

            long long T = 0;
            if (vf != 0.0f) {
                int k; (void)frexpf(vf, &k);                // |vf| in [2^(k-1),2^k)
                const double u = ldexp(1.0, k - 24);
                const double q = gcd / u;                   // exact (u = 2^j)
                if (q - floor(q) == 0.5) { s_bad = 1; break; }  // tie binade
                const double B = (V > 0.0) ? ldexp(1.0, k - 1) : -ldexp(1.0, k);
                // T = max{t>=0 : s_{t-1} = V+(t-1)c+gc stays in v's binade}
                double tt = (V + gcd - B) / (-c) + 1.0;
                T = tt > 0.0 ? (long long)tt : 0;
                int g2 = 0;
                if (V > 0.0) {                              // s >= B required
                    while (T > 0 && V + (double)(T - 1) * c + gcd <  B && ++g2 < 16) --T;
                    while (V + (double)T * c + gcd >= B && ++g2 < 16) ++T;
                } else {                                    // s > B required
                    while (T > 0 && V + (double)(T - 1) * c + gcd <= B && ++g2 < 16) --T;
                    while (V + (double)T * c + gcd >  B && ++g2 < 16) ++T;
                }
                if (g2 >= 16) { s_bad = 1; break; }
                if (T < 0) T = 0;
            }
            if (T > rem) T = rem;
            if (T > 0) {                                    // main segment
                s_m[nseg] = (int)m; s_V[nseg] = V; s_c[nseg] = c; s_P[nseg] = P; ++nseg;
                P += dtd * ((double)T * V + c * ((double)T * (double)(T - 1) * 0.5));
                V += (double)T * c;                         // exact dyadics
                m += T;
                if (m >= NSTEPS) break;
            }
            // boundary step: 1-step segment, increment from direct f32 ops
            const float vf2 = (float)V;
            if ((double)vf2 != V) { s_bad = 1; break; }
            const float vb = __fadd_rn(vf2, gdtf);
            const double cb = (double)vb - V;
            s_m[nseg] = (int)m; s_V[nseg] = V; s_c[nseg] = cb; s_P[nseg] = P; ++nseg;
            P += dtd * V;
            V += cb;
            m += 1;
        }
        if (m < NSTEPS) s_bad = 1;
        s_nseg = nseg;
        s_m[nseg] = 0x7fffffff;                             // sentinel
    }
    __syncthreads();

    // ===== Phase 1b: wave-parallel verification of the analytic staircase ===
    if (!s_bad) {
        const int nseg = s_nseg;
        bool ok = (nseg > 0);
        for (int i = lane; i < nseg; i += 64) {
            const double Vi = s_V[i], ci = s_c[i];
            const long long mi = s_m[i];
            const long long me = (i + 1 < nseg) ? (long long)s_m[i + 1] : NSTEPS;
            const long long len = me - mi;
            ok = ok && (len >= 1);
            const float vfi = (float)Vi;
            ok = ok && ((double)vfi == Vi);
            const float vn = __fadd_rn(vfi, gdtf);
            ok = ok && ((double)vn - Vi == ci);             // start increment
            const double Ve = Vi + (double)(len - 1) * ci;
            const float vfe = (float)Ve;
            ok = ok && ((double)vfe == Ve);                 // end representable
            const float vne = __fadd_rn(vfe, gdtf);
            ok = ok && ((double)vne - Ve == ci);            // end increment
            if (len > 1) {
                ok = ok && same_binade_f32(vfe, vfi);       // v-convexity
                int e0, e1;
                (void)frexp(Vi + gcd, &e0);
                (void)frexp(Ve + gcd, &e1);
                ok = ok && (e0 == e1);                      // s-convexity
                int k; (void)frexpf(vfi, &k);
                const double u = ldexp(1.0, k - 24);
                const double q = gcd / u;
                ok = ok && (q - floor(q) != 0.5);           // non-tie
            }
            if (i + 1 < nseg)
                ok = ok && (s_V[i + 1] == Vi + (double)len * ci);  // chain
        }
        const unsigned long long good = __ballot(ok);
        if (lane == 0 && good != ~0ULL) s_bad = 1;
    }
    __syncthreads();

    // ===== Phase 1c: fallback — r6 serial ballot staircase ==================
    if (s_bad) {
        double V = (double)vel0[1];
        double P = (double)pos0[1];
        long long m = 0;
        int nseg = 0;
        while (m < NSTEPS && nseg < SEGCAP) {
            const float vf  = (float)V;
            const float vn1 = __fadd_rn(vf, gdtf);
            const double c  = (double)vn1 - V;
            const long long rem = NSTEPS - m;
            long long Lb = rem;
            const float cf = (float)c;
            if (vf == 0.0f) {
                Lb = 64;
            } else if (cf != 0.0f) {
                int k; (void)frexpf(vf, &k);
                float s = vf < 0.0f ? -1.0f : 1.0f;
                float B = ((vf < 0.0f) == (cf < 0.0f)) ? ldexpf(s, k) : ldexpf(s, k - 1);
                float r = __fdividef(B - vf, cf);
                if (r >= 0.0f && r < 4.0e9f) Lb = (long long)r + 1;
            }
            long long Lhi = Lb + 2;
            if (Lhi > rem) Lhi = rem;
            if (Lhi < 1) Lhi = 1;

            long long L = 1, base = Lhi;
            for (int round = 0; round < 32; ++round) {
                const long long candL = base - 63 + (long long)lane;
                bool valid = false;
                if (candL >= 1) {
                    const double ve = V + (double)(candL - 1) * c;
                    const float vef = (float)ve;
                    const float vn2 = __fadd_rn(vef, gdtf);
                    valid = ((double)vef == ve)
                         && same_binade_f32(vef, vf)
                         && ((double)vn2 - ve == c);
                }
                unsigned long long msk = __ballot(valid);
                if (msk) { L = base - 63 + (long long)(63 - __clzll(msk)); break; }
                base -= 64;
                if (base < 1) break;
            }
            if (L < 1) L = 1;
            if (L > rem) L = rem;

            if (lane == 0) { s_m[nseg] = (int)m; s_V[nseg] = V; s_c[nseg] = c; s_P[nseg] = P; }
            ++nseg;
            P += dtd * ((double)L * V + c * ((double)L * (double)(L - 1) * 0.5));
            V += (double)L * c;
            m += L;
        }
        if (lane == 0) { s_nseg = nseg; s_m[nseg] = 0x7fffffff; }
    }
    __syncthreads();

    // ===== Publish segments =================================================
    const int nseg = s_nseg;
    for (int i = lane; i <= nseg; i += 64) {
        g_segm[i] = s_m[i];
        if (i < nseg) { g_segV[i] = s_V[i]; g_segc[i] = s_c[i]; g_segP[i] = s_P[i]; }
    }
    if (lane == 0) counts[0] = nseg;

    // ===== Phase 2: pos run-events from NS (r6 verbatim) ====================
    int lo = 0, hi = nseg - 1;
    while (lo < hi) { int mid = (lo + hi + 1) >> 1;
                      if ((long long)s_m[mid] <= NS) lo = mid; else hi = mid - 1; }
    int jj = lo;
    const double t0 = (double)(NS - s_m[jj]);
    double vel = s_V[jj] + t0 * s_c[jj];                    // exact scan vel at NS
    double P2  = s_P[jj] + dtd * (t0 * s_V[jj] + s_c[jj] * (t0 * (t0 - 1.0) * 0.5));
    double pos = (double)(float)P2;                         // snap model pos to grid
    long long n = NS;
    int nrun = 0;
    while (n < NSTEPS - 1 && nrun < runcap) {
        while (s_m[jj + 1] <= (int)n) ++jj;                 // sentinel stops
        const double cv = s_c[jj];
        long long Lcap = (long long)s_m[jj + 1] - n;
        const long long rem = (NSTEPS - 1) - n;
        if (Lcap > rem) Lcap = rem;

        const float pf = (float)pos;
        const float vf2 = (float)vel;
        const float dstep = __fmul_rn(vf2, dtf);
        const float pn1 = __fadd_rn(pf, dstep);
        const double inc = (double)pn1 - pos;               // exact f32 pos increment

        long long La = Lcap, Lc = Lcap;
        const float incf = (float)inc;
        if (pf == 0.0f) {
            La = 64;
        } else if (incf != 0.0f) {                          // pos binade exit
            int k; (void)frexpf(pf, &k);
            float s = pf < 0.0f ? -1.0f : 1.0f;
            float B = ((pf < 0.0f) == (incf < 0.0f)) ? ldexpf(s, k) : ldexpf(s, k - 1);
            float r = __fdividef(B - pf, incf);
            if (r >= 0.0f && r < 4.0e9f) { La = (long long)r - 1; if (La < 0) La = 0; }
        }
        const double dd = cv * dtd;
        if (dd != 0.0 && pf != 0.0f) {                      // increment cell crossing
            int k; (void)frexpf(pf, &k);
            const float ulpf = ldexpf(1.0f, k - 24);
            const double d0 = (double)dstep;
            const double T = inc + (dd < 0.0 ? -0.5 : 0.5) * (double)ulpf;
            float r = __fdividef((float)(T - d0), (float)dd);
            if (r >= 0.0f && r < 4.0e9f) { Lc = (long long)r + 2; if (Lc < 1) Lc = 1; }
        }
        long long Lhi = La < Lc ? La : Lc;
        Lhi += 3;
        if (Lhi > Lcap) Lhi = Lcap;
        if (Lhi < 1) Lhi = 1;

        long long L = 1, base = Lhi;
        for (int round = 0; round < 32; ++round) {
            const long long candL = base - 63 + (long long)lane;
            bool valid = false;
            if (candL >= 1) {
                const double pe = pos + (double)(candL - 1) * inc;  // exact dyadics
                const double ve = vel + (double)(candL - 1) * cv;
                const float pef = (float)pe;
                const float vef = (float)ve;
                const float d2  = __fmul_rn(vef, dtf);
                const float pn2 = __fadd_rn(pef, d2);
                valid = ((double)pef == pe)
                     && same_binade_f32(pef, pf)
                     && ((double)vef == ve)
                     && ((double)pn2 - pe == inc);
            }
            unsigned long long msk = __ballot(valid);
            if (msk) { L = base - 63 + (long long)(63 - __clzll(msk)); break; }
            base -= 64;
            if (base < 1) break;
        }
        if (L < 1) L = 1;
        if (L > rem) L = rem;

        if (lane == 0) { g_rn0[nrun] = (int)n; g_rpos[nrun] = pos; g_rinc[nrun] = inc; }
        ++nrun;
        pos += (double)L * inc;
        vel += (double)L * cv;
        n += L;
    }
    if (lane == 0) counts[1] = nrun;
}

__global__ __launch_bounds__(256) void fill(
        const float* __restrict__ pos0, const float* __restrict__ vel0,
        const int* __restrict__ counts,
        const int* __restrict__ g_segm, const double* __restrict__ g_segV,
        const double* __restrict__ g_segc, const double* __restrict__ g_segP,
        const int* __restrict__ g_rn0, const double* __restrict__ g_rpos,
        const double* __restrict__ g_rinc,
        float4* __restrict__ out, long long npairs)
{
    __shared__ int    t_sm[SEGCAP + 1];
    __shared__ double t_sV[SEGCAP], t_sc[SEGCAP], t_sP[SEGCAP];
    __shared__ int    t_rn[RUN_LDS];
    __shared__ double t_rp[RUN_LDS], t_ri[RUN_LDS];

    const float dtf = 0.01f;
    const double dtd = (double)dtf;
    const double p0x = (double)pos0[0];
    const double cx  = (double)__fmul_rn(vel0[0], dtf);  // constant f32 x-increment

    const int nseg = counts[0];
    const int nrun = counts[1];
    const bool segL = (nseg > 0 && nseg <= SEGCAP);
    const bool runL = (nrun > 0 && nrun <= RUN_LDS);
    if (segL) for (int i = threadIdx.x; i <= nseg; i += blockDim.x) {
        t_sm[i] = g_segm[i];
        if (i < nseg) { t_sV[i] = g_segV[i]; t_sc[i] = g_segc[i]; t_sP[i] = g_segP[i]; }
    }
    if (runL) for (int i = threadIdx.x; i < nrun; i += blockDim.x) {
        t_rn[i] = g_rn0[i]; t_rp[i] = g_rpos[i]; t_ri[i] = g_rinc[i];
    }
    __syncthreads();

    const int*    pm = segL ? (const int*)t_sm    : g_segm;
    const double* pV = segL ? (const double*)t_sV : g_segV;
    const double* pc = segL ? (const double*)t_sc : g_segc;
    const double* pP = segL ? (const double*)t_sP : g_segP;
    const int*    rn = runL ? (const int*)t_rn    : g_rn0;
    const double* rp = runL ? (const double*)t_rp : g_rpos;
    const double* ri = runL ? (const double*)t_ri : g_rinc;

    const long long stride = (long long)gridDim.x * blockDim.x;
    for (long long i = (long long)blockIdx.x * blockDim.x + threadIdx.x;
         i < npairs; i += stride) {
        const long long m0 = 2 * i, m1 = m0 + 1;
        float4 o;
        o.x = (float)(p0x + (double)m0 * cx);
        o.z = (float)(p0x + (double)m1 * cx);

        if (m1 < NS || nrun <= 0) {  // exact-vel integral model (NS even)
            const int t0 = (int)m0;
            int lo = 0, hi = nseg - 1;
            while (lo < hi) { int mid = (lo + hi + 1) >> 1; if (pm[mid] <= t0) lo = mid; else hi = mid - 1; }
            double t = (double)(m0 - pm[lo]);
            o.y = (float)(pP[lo] + dtd * (t * pV[lo] + pc[lo] * (t * (t - 1.0) * 0.5)));
            const int j1 = (pm[lo + 1] <= (int)m1) ? lo + 1 : lo;
            t = (double)(m1 - pm[j1]);
            o.w = (float)(pP[j1] + dtd * (t * pV[j1] + pc[j1] * (t * (t - 1.0) * 0.5)));
        } else {        // run-event region
            const int t0 = (int)m0;
            int lo = 0, hi = nrun - 1;
            while (lo < hi) { int mid = (lo + hi + 1) >> 1; if (rn[mid] <= t0) lo = mid; else hi = mid - 1; }
            o.y = (float)(rp[lo] + (double)(m0 - rn[lo]) * ri[lo]);
            const int j1 = (lo + 1 < nrun && rn[lo + 1] <= (int)m1) ? lo + 1 : lo;
            o.w = (float)(rp[j1] + (double)(m1 - rn[j1]) * ri[j1]);
        }
        out[i] = o;
    }
}

extern "C" void kernel_launch(void* const* d_in, const int* in_sizes, int n_in,
                              void* d_out, int out_size, void* d_ws, size_t ws_size,
                              hipStream_t stream) {
    // Inputs: [0] ball_mass (unused), [1] initial_position[2], [2] initial_velocity[2].
    const float* pos0 = (const float*)d_in[1];
    const float* vel0 = (const float*)d_in[2];

    char* base = (char*)d_ws;
    size_t off = 64;
    int* counts = (int*)base;
    double* g_segV = (double*)(base + off); off += (size_t)SEGCAP * 8;
    double* g_segc = (double*)(base + off); off += (size_t)SEGCAP * 8;
    double* g_segP = (double*)(base + off); off += (size_t)SEGCAP * 8;
    double* g_rpos = (double*)(base + off); off += (size_t)RUNCAP * 8;
    double* g_rinc = (double*)(base + off); off += (size_t)RUNCAP * 8;
    int* g_segm = (int*)(base + off); off += ((size_t)(SEGCAP + 1) * 4 + 7) & ~(size_t)7;
    int* g_rn0  = (int*)(base + off);

    prepass<<<1, 64, 0, stream>>>(pos0, vel0, counts,
                                  g_segm, g_segV, g_segc, g_segP,
                                  g_rn0, g_rpos, g_rinc, RUNCAP);

    const long long npairs = (long long)out_size / 4;  // 5,000,000 float4s
    fill<<<2048, 256, 0, stream>>>(pos0, vel0, counts,
                                   g_segm, g_segV, g_segc, g_segP,
                                   g_rn0, g_rpos, g_rinc,
                                   (float4*)d_out, npairs);
}